// Round 8
// baseline (652.409 us; speedup 1.0000x reference)
//
#include <hip/hip_runtime.h>
#include <hip/hip_fp16.h>
#include <hip/hip_cooperative_groups.h>

namespace cg = cooperative_groups;

// GraphSAGE 3-layer. 5 dispatches:
//   k_prep (cooperative): tohalf + hist + scan + binscatter + build (CSR)
//   k_agg, k_gemm, k_agg, k_gemm2fin (cooperative: GEMM2 + fused layer-3)
// fp16 feature tables (N+1 rows, row N zeroed); agg fp16; h2 never built.
//
// ws: offs | scol | xh | h1 | aggh | tarr | sarr
//     (sort scratch ebuf/hist/histsc/part aliases the aggh region)

#define CH 64
#define BKT_SHIFT 9
#define BKT_ROWS 512
#define PBLK 512   // prep grid (co-resident: 2 blocks/CU at 54 KB LDS)
#define SCAP 12288 // LDS staging capacity in build stage

// ============ cooperative CSR-build + convert kernel ============
__global__ __launch_bounds__(256) void k_prep(
    const float* __restrict__ x, __half* __restrict__ xh, __half* __restrict__ h1,
    const int* __restrict__ row, const int* __restrict__ col,
    int* __restrict__ hist, int* __restrict__ histsc, int* __restrict__ part,
    int* __restrict__ ebuf, int* __restrict__ offs, int* __restrict__ scol,
    int N, int E, int nbk, int per_blk)
{
    __shared__ int sh[1280 + SCAP];  // 54.3 KB, unioned across stages
    cg::grid_group grid = cg::this_grid();
    int t = threadIdx.x;
    int b = blockIdx.x;
    int gtid = b * 256 + t;
    const int nth = PBLK * 256;

    // ---- stage 0: x -> fp16 table + zero dummy rows ----
    {
        int M4 = N * CH / 4;
        for (int idx = gtid; idx < M4; idx += nth) {
            float4 v = *(const float4*)(x + (size_t)idx * 4);
            union { __half2 h[2]; float2 f; } u;
            u.h[0] = __floats2half2_rn(v.x, v.y);
            u.h[1] = __floats2half2_rn(v.z, v.w);
            *(float2*)(xh + (size_t)idx * 4) = u.f;
        }
        if (b == 0 && t < 16) {
            float4 z = {0.f, 0.f, 0.f, 0.f};
            if (t < 8) ((float4*)(xh + (size_t)N * CH))[t] = z;
            else       ((float4*)(h1 + (size_t)N * CH))[t - 8] = z;
        }
    }
    // ---- stage 1: per-block bucket histogram, hist[bucket][PBLK] ----
    {
        sh[t] = 0;
        __syncthreads();
        int s = b * per_blk;
        int e = min(s + per_blk, E);
        for (int i = s + t; i < e; i += 256)
            atomicAdd(&sh[row[i] >> BKT_SHIFT], 1);
        __syncthreads();
        if (t < nbk) hist[t * PBLK + b] = sh[t];
    }
    grid.sync();
    const int M = nbk * PBLK;
    const int mb = (M + 1023) >> 10;
    // ---- stage 2a: block sums ----
    if (b < mb) {
        int g0 = b * 1024 + t * 4;
        int s = 0;
#pragma unroll
        for (int i = 0; i < 4; ++i)
            if (g0 + i < M) s += hist[g0 + i];
        sh[t] = s;
        __syncthreads();
        for (int off = 128; off >= 1; off >>= 1) {
            if (t < off) sh[t] += sh[t + off];
            __syncthreads();
        }
        if (t == 0) part[b] = sh[0];
    }
    grid.sync();
    // ---- stage 2b: parallel exclusive scan of partials (block 0) ----
    if (b == 0) {
        int v = (t < mb) ? part[t] : 0;
        sh[t] = v;
        __syncthreads();
        for (int off = 1; off < 256; off <<= 1) {
            int u = (t >= off) ? sh[t - off] : 0;
            __syncthreads();
            sh[t] += u;
            __syncthreads();
        }
        if (t < mb) part[t] = sh[t] - v;
    }
    grid.sync();
    // ---- stage 2c: full exclusive scan -> histsc ----
    if (b < mb) {
        int g0 = b * 1024 + t * 4;
        int d[4];
        int s = 0;
#pragma unroll
        for (int i = 0; i < 4; ++i) {
            d[i] = (g0 + i < M) ? hist[g0 + i] : 0;
            s += d[i];
        }
        sh[t] = s;
        __syncthreads();
        for (int off = 1; off < 256; off <<= 1) {
            int u = (t >= off) ? sh[t - off] : 0;
            __syncthreads();
            sh[t] += u;
            __syncthreads();
        }
        int run = part[b] + sh[t] - s;
#pragma unroll
        for (int i = 0; i < 4; ++i) {
            if (g0 + i < M) histsc[g0 + i] = run;
            run += d[i];
        }
    }
    grid.sync();
    // ---- stage 3: binscatter packed (rowlocal<<17 | col) into ebuf ----
    {
        sh[t] = (t < nbk) ? histsc[t * PBLK + b] : 0;
        __syncthreads();
        int s = b * per_blk;
        int e = min(s + per_blk, E);
        for (int i = s + t; i < e; i += 256) {
            int r = row[i];
            int bk = r >> BKT_SHIFT;
            int p = atomicAdd(&sh[bk], 1);
            ebuf[p] = ((r & (BKT_ROWS - 1)) << 17) | col[i];
        }
    }
    grid.sync();
    // ---- stage 4: per-bucket CSR build (blocks < nbk) ----
    if (b < nbk) {
        int* cnt  = sh;          // 512
        int* loff = sh + 512;    // 512
        int* ts   = sh + 1024;   // 256
        int* sbuf = sh + 1280;   // SCAP
        int g0 = histsc[b * PBLK];
        int g1 = (b + 1 < nbk) ? histsc[(b + 1) * PBLK] : E;
        cnt[t] = 0;
        cnt[t + 256] = 0;
        __syncthreads();
        for (int i = g0 + t; i < g1; i += 256)
            atomicAdd(&cnt[((unsigned)ebuf[i]) >> 17], 1);
        __syncthreads();
        int c0 = cnt[2 * t], c1 = cnt[2 * t + 1];
        ts[t] = c0 + c1;
        __syncthreads();
        for (int off = 1; off < 256; off <<= 1) {
            int v = (t >= off) ? ts[t - off] : 0;
            __syncthreads();
            ts[t] += v;
            __syncthreads();
        }
        int ex = ts[t] - (c0 + c1);
        loff[2 * t] = ex;
        loff[2 * t + 1] = ex + c0;
        __syncthreads();
        int r0 = b << BKT_SHIFT;
        for (int r = t; r < BKT_ROWS; r += 256)
            if (r0 + r < N) offs[r0 + r] = g0 + loff[r];
        if (b == nbk - 1 && t == 0) offs[N] = E;
        cnt[t] = 0;
        cnt[t + 256] = 0;
        __syncthreads();
        int sz = g1 - g0;
        if (sz <= SCAP) {
            for (int i = g0 + t; i < g1; i += 256) {
                unsigned v = (unsigned)ebuf[i];
                int rl = v >> 17;
                int p = atomicAdd(&cnt[rl], 1);
                sbuf[loff[rl] + p] = (int)(v & 0x1FFFFu);
            }
            __syncthreads();
            for (int i = t; i < sz; i += 256) scol[g0 + i] = sbuf[i];
        } else {
            for (int i = g0 + t; i < g1; i += 256) {
                unsigned v = (unsigned)ebuf[i];
                int rl = v >> 17;
                int p = atomicAdd(&cnt[rl], 1);
                scol[g0 + loff[rl] + p] = (int)(v & 0x1FFFFu);
            }
        }
    }
}

// ============ mean-aggregate (unchanged hot kernel) ============
__global__ __launch_bounds__(256) void k_agg(const float4* __restrict__ X4,
                                             const int* __restrict__ offs,
                                             const int* __restrict__ scol,
                                             __half* __restrict__ AGGH, int N, int Em1) {
    int node = blockIdx.x * 4 + (threadIdx.x >> 6);
    int lane = threadIdx.x & 63;
    if (node >= N) return;
    int s = offs[node], e = offs[node + 1];
    int sub = lane & 7;
    int grp = lane >> 3;
    int j = s + grp;
    int i0 = scol[min(j, Em1)];       i0 = (j < e)      ? i0 : N;
    int i1 = scol[min(j + 8, Em1)];   i1 = (j + 8 < e)  ? i1 : N;
    int i2 = scol[min(j + 16, Em1)];  i2 = (j + 16 < e) ? i2 : N;
    int i3 = scol[min(j + 24, Em1)];  i3 = (j + 24 < e) ? i3 : N;
    float4 r0 = X4[(size_t)i0 * 8 + sub];
    float4 r1 = X4[(size_t)i1 * 8 + sub];
    float4 r2 = X4[(size_t)i2 * 8 + sub];
    float4 r3 = X4[(size_t)i3 * 8 + sub];
    float a[8];
#pragma unroll
    for (int k = 0; k < 8; ++k) a[k] = 0.f;
    {
        const __half2* h0 = (const __half2*)&r0;
        const __half2* h1 = (const __half2*)&r1;
        const __half2* h2 = (const __half2*)&r2;
        const __half2* h3 = (const __half2*)&r3;
#pragma unroll
        for (int p = 0; p < 4; ++p) {
            float2 f0 = __half22float2(h0[p]);
            float2 f1 = __half22float2(h1[p]);
            float2 f2 = __half22float2(h2[p]);
            float2 f3 = __half22float2(h3[p]);
            a[2 * p]     += (f0.x + f1.x) + (f2.x + f3.x);
            a[2 * p + 1] += (f0.y + f1.y) + (f2.y + f3.y);
        }
    }
    for (j += 32; j < e; j += 8) {  // rare tail: deg > 32
        float4 r = X4[(size_t)scol[j] * 8 + sub];
        const __half2* h = (const __half2*)&r;
#pragma unroll
        for (int p = 0; p < 4; ++p) {
            float2 f = __half22float2(h[p]);
            a[2 * p]     += f.x;
            a[2 * p + 1] += f.y;
        }
    }
#pragma unroll
    for (int off = 32; off >= 8; off >>= 1)
#pragma unroll
        for (int k = 0; k < 8; ++k)
            a[k] += __shfl_down(a[k], off, 64);
    if (lane < 8) {
        float inv = (e > s) ? 1.0f / (float)(e - s) : 1.0f;
        union { __half2 h[4]; float4 f; } u;
        u.h[0] = __floats2half2_rn(a[0] * inv, a[1] * inv);
        u.h[1] = __floats2half2_rn(a[2] * inv, a[3] * inv);
        u.h[2] = __floats2half2_rn(a[4] * inv, a[5] * inv);
        u.h[3] = __floats2half2_rn(a[6] * inv, a[7] * inv);
        *(float4*)(AGGH + (size_t)node * CH + sub * 8) = u.f;
    }
}

// ---- shared A-tile staging (fp16 A + fp16 AGG -> fp32 LDS [k][n]) ----
__device__ __forceinline__ void stage_a(const __half* __restrict__ A,
                                        const __half* __restrict__ AGGH,
                                        float (*As)[68], int t, int base, int N) {
    int n = t >> 2;
    int c0 = (t & 3) * 16;
    int gn = base + n;
    if (gn < N) {
        const float4* xr = (const float4*)(A + (size_t)gn * CH + c0);
        const float4* gr = (const float4*)(AGGH + (size_t)gn * CH + c0);
#pragma unroll
        for (int q = 0; q < 2; ++q) {
            union { float4 f; __half2 h[4]; } u;
            u.f = xr[q];
#pragma unroll
            for (int p = 0; p < 4; ++p) {
                As[c0 + q * 8 + 2 * p + 0][n] = __low2float(u.h[p]);
                As[c0 + q * 8 + 2 * p + 1][n] = __high2float(u.h[p]);
            }
            union { float4 f; __half2 h[4]; } g;
            g.f = gr[q];
#pragma unroll
            for (int p = 0; p < 4; ++p) {
                As[64 + c0 + q * 8 + 2 * p + 0][n] = __low2float(g.h[p]);
                As[64 + c0 + q * 8 + 2 * p + 1][n] = __high2float(g.h[p]);
            }
        }
    } else {
#pragma unroll
        for (int i = 0; i < 16; ++i) {
            As[c0 + i][n] = 0.f;
            As[64 + c0 + i][n] = 0.f;
        }
    }
}

__device__ __forceinline__ void stage_w(const float* __restrict__ W,
                                        float (*Ws)[68], int t) {
    int o = t >> 2;
    int k0 = (t & 3) * 32;
    const float4* wr = (const float4*)(W + o * 128 + k0);
#pragma unroll
    for (int q = 0; q < 8; ++q) {
        float4 v = wr[q];
        Ws[k0 + q * 4 + 0][o] = v.x;
        Ws[k0 + q * 4 + 1][o] = v.y;
        Ws[k0 + q * 4 + 2][o] = v.z;
        Ws[k0 + q * 4 + 3][o] = v.w;
    }
}

#define GEMM_CORE(As, Ws, acc, n0, o0)                                          \
    _Pragma("unroll 4")                                                          \
    for (int k = 0; k < 128; ++k) {                                              \
        float4 a = *(const float4*)&As[k][n0];                                   \
        float4 w = *(const float4*)&Ws[k][o0];                                   \
        acc[0][0] += a.x * w.x; acc[0][1] += a.x * w.y; acc[0][2] += a.x * w.z; acc[0][3] += a.x * w.w; \
        acc[1][0] += a.y * w.x; acc[1][1] += a.y * w.y; acc[1][2] += a.y * w.z; acc[1][3] += a.y * w.w; \
        acc[2][0] += a.z * w.x; acc[2][1] += a.z * w.y; acc[2][2] += a.z * w.z; acc[2][3] += a.z * w.w; \
        acc[3][0] += a.w * w.x; acc[3][1] += a.w * w.y; acc[3][2] += a.w * w.z; acc[3][3] += a.w * w.w; \
    }

// ---- layer-1: h1 = relu(cat(xh,agg).W1^T + b1), fp16 out ----
__global__ __launch_bounds__(256) void k_gemm(const __half* __restrict__ A,
                                              const __half* __restrict__ AGGH,
                                              const float* __restrict__ W,
                                              const float* __restrict__ bias,
                                              __half* __restrict__ OUT, int N) {
    __shared__ float As[128][68];
    __shared__ float Ws[128][68];
    int t = threadIdx.x;
    int base = blockIdx.x * 64;
    stage_w(W, Ws, t);
    stage_a(A, AGGH, As, t, base, N);
    __syncthreads();
    int o0 = (t & 15) * 4;
    int n0 = (t >> 4) * 4;
    float acc[4][4];
#pragma unroll
    for (int i = 0; i < 4; ++i)
#pragma unroll
        for (int jj = 0; jj < 4; ++jj) acc[i][jj] = 0.f;
    GEMM_CORE(As, Ws, acc, n0, o0);
    float4 bv = *(const float4*)&bias[o0];
#pragma unroll
    for (int i = 0; i < 4; ++i) {
        int gn = base + n0 + i;
        if (gn < N) {
            float rx = fmaxf(acc[i][0] + bv.x, 0.f);
            float ry = fmaxf(acc[i][1] + bv.y, 0.f);
            float rz = fmaxf(acc[i][2] + bv.z, 0.f);
            float rw = fmaxf(acc[i][3] + bv.w, 0.f);
            union { __half2 h[2]; float2 f; } u;
            u.h[0] = __floats2half2_rn(rx, ry);
            u.h[1] = __floats2half2_rn(rz, rw);
            *(float2*)(OUT + (size_t)gn * CH + o0) = u.f;
        }
    }
}

// ---- cooperative: layer-2 GEMM (+layer-3 dots) grid-stride, then fin ----
__global__ __launch_bounds__(256) void k_gemm2fin(
    const __half* __restrict__ A, const __half* __restrict__ AGGH,
    const float* __restrict__ W, const float* __restrict__ bias,
    const float* __restrict__ W3,
    float* __restrict__ tarr, float* __restrict__ sarr,
    const int* __restrict__ offs, const int* __restrict__ scol,
    const float* __restrict__ b3, float* __restrict__ out, int N)
{
    __shared__ float As[128][68];
    __shared__ float Ws[128][68];
    cg::grid_group grid = cg::this_grid();
    int t = threadIdx.x;
    int ntiles = (N + 63) / 64;
    stage_w(W, Ws, t);
    int o0 = (t & 15) * 4;
    int n0 = (t >> 4) * 4;
    float4 bv  = *(const float4*)&bias[o0];
    float4 w3s = *(const float4*)&W3[o0];
    float4 w3a = *(const float4*)&W3[64 + o0];
    for (int tile = blockIdx.x; tile < ntiles; tile += gridDim.x) {
        int base = tile * 64;
        __syncthreads();  // As reuse guard
        stage_a(A, AGGH, As, t, base, N);
        __syncthreads();
        float acc[4][4];
#pragma unroll
        for (int i = 0; i < 4; ++i)
#pragma unroll
            for (int jj = 0; jj < 4; ++jj) acc[i][jj] = 0.f;
        GEMM_CORE(As, Ws, acc, n0, o0);
#pragma unroll
        for (int i = 0; i < 4; ++i) {
            float rx = fmaxf(acc[i][0] + bv.x, 0.f);
            float ry = fmaxf(acc[i][1] + bv.y, 0.f);
            float rz = fmaxf(acc[i][2] + bv.z, 0.f);
            float rw = fmaxf(acc[i][3] + bv.w, 0.f);
            float tp = rx * w3s.x + ry * w3s.y + rz * w3s.z + rw * w3s.w;
            float sp = rx * w3a.x + ry * w3a.y + rz * w3a.z + rw * w3a.w;
#pragma unroll
            for (int off = 8; off >= 1; off >>= 1) {
                tp += __shfl_down(tp, off, 16);
                sp += __shfl_down(sp, off, 16);
            }
            int gn = base + n0 + i;
            if ((t & 15) == 0 && gn < N) {
                tarr[gn] = tp;
                sarr[gn] = sp;
            }
        }
    }
    grid.sync();
    // fin: out[n] = t[n] + mean_j s[col_j] + b3
    int gtid = blockIdx.x * 256 + t;
    int nth = gridDim.x * 256;
    for (int n = gtid; n < N; n += nth) {
        int s = offs[n], e = offs[n + 1];
        float s0 = 0.f, s1 = 0.f, s2 = 0.f, s3 = 0.f;
        int j = s;
        for (; j + 4 <= e; j += 4) {
            s0 += sarr[scol[j]];
            s1 += sarr[scol[j + 1]];
            s2 += sarr[scol[j + 2]];
            s3 += sarr[scol[j + 3]];
        }
        for (; j < e; ++j) s0 += sarr[scol[j]];
        float inv = (e > s) ? 1.0f / (float)(e - s) : 1.0f;
        out[n] = tarr[n] + ((s0 + s1) + (s2 + s3)) * inv + b3[0];
    }
}

extern "C" void kernel_launch(void* const* d_in, const int* in_sizes, int n_in,
                              void* d_out, int out_size, void* d_ws, size_t ws_size,
                              hipStream_t stream) {
    const float* x   = (const float*)d_in[0];
    const int* eidx  = (const int*)d_in[1];
    const float* W1  = (const float*)d_in[2];
    const float* b1  = (const float*)d_in[3];
    const float* W2  = (const float*)d_in[4];
    const float* b2  = (const float*)d_in[5];
    const float* W3  = (const float*)d_in[6];
    const float* b3  = (const float*)d_in[7];
    float* out = (float*)d_out;

    int N = in_sizes[0] / CH;
    int E = in_sizes[1] / 2;
    const int* row = eidx;
    const int* col = eidx + E;

    int offs_sz = ((N + 1 + 3) / 4) * 4;
    int e_sz    = ((E + 3) / 4) * 4;
    size_t tbl  = (size_t)(N + 1) * CH;

    int* offs    = (int*)d_ws;
    int* scol    = offs + offs_sz;
    __half* xh   = (__half*)(scol + e_sz);
    __half* h1   = xh + tbl;
    __half* aggh = h1 + tbl;
    float* tarr  = (float*)(aggh + (size_t)N * CH);
    float* sarr  = tarr + N;
    // sort scratch aliases aggh region (dead before aggh's first write)
    int* ebuf   = (int*)aggh;                  // E
    int nbk     = (N + BKT_ROWS - 1) >> BKT_SHIFT;
    int* hist   = ebuf + e_sz;                 // nbk*PBLK
    int* histsc = hist + (size_t)nbk * PBLK;   // nbk*PBLK
    int* part   = histsc + (size_t)nbk * PBLK; // <=512

    int per_blk = (E + PBLK - 1) / PBLK;
    int abl = (N + 3) / 4;
    int gbl = (N + 63) / 64;
    int Em1 = E - 1;

    // 1) cooperative CSR build + fp16 convert
    {
        void* args[] = {&x, &xh, &h1, &row, &col, &hist, &histsc, &part,
                        &ebuf, &offs, &scol, &N, &E, &nbk, &per_blk};
        hipLaunchCooperativeKernel((void*)k_prep, dim3(PBLK), dim3(256),
                                   args, 0, stream);
    }
    // 2) layer-1 aggregate
    k_agg<<<abl, 256, 0, stream>>>((const float4*)xh, offs, scol, aggh, N, Em1);
    // 3) layer-1 GEMM
    k_gemm<<<gbl, 256, 0, stream>>>(xh, aggh, W1, b1, h1, N);
    // 4) layer-2 aggregate
    k_agg<<<abl, 256, 0, stream>>>((const float4*)h1, offs, scol, aggh, N, Em1);
    // 5) cooperative layer-2 GEMM + fused layer-3
    {
        void* args[] = {&h1, &aggh, &W2, &b2, &W3, &tarr, &sarr,
                        &offs, &scol, &b3, &out, &N};
        hipLaunchCooperativeKernel((void*)k_gemm2fin, dim3(PBLK), dim3(256),
                                   args, 0, stream);
    }
}

// Round 9
// 337.224 us; speedup vs baseline: 1.9346x; 1.9346x over previous
//
#include <hip/hip_runtime.h>
#include <hip/hip_fp16.h>

// GraphSAGE 3-layer. CSR via two-level counting sort with atomic bucket
// offsets (no big scan; 196-entry bucket-base scan done by last-arriving
// hist block). fp16 feature tables (N+1 rows, row N zeroed). agg fp16.
// Layer-2 GEMM fuses layer-3 dots; h2 never materialized.
// 8 kernel dispatches + 1 tiny memset. (R8's cooperative grid.sync was a
// 324 us stall — reverted to plain dispatches.)
//
// ws: offs | scol | xh | h1 | aggh | tarr | sarr
//     aggh region aliases: ebuf[E] | hoff[nbk*NBLK] | btotal[nbk] | done[1] | bstart[nbk+1]

#define CH 64
#define BKT_SHIFT 9
#define BKT_ROWS 512
#define NBLK 256   // hist/binscatter blocks; requires nbk <= 256
#define SCAP 12288 // LDS staging capacity in k_build

// ---- hist: fp16 convert + zero rows + bucket histogram + atomic offsets;
//      last-arriving block scans bucket totals -> bstart ----
__global__ __launch_bounds__(256) void k_hist(
    const float* __restrict__ x, __half* __restrict__ xh, __half* __restrict__ h1,
    const int* __restrict__ row,
    int* __restrict__ hoff, int* __restrict__ btotal, int* __restrict__ done,
    int* __restrict__ bstart,
    int N, int E, int nbk, int per_blk)
{
    __shared__ int h[256];
    __shared__ int lastflag;
    int t = threadIdx.x;
    int b = blockIdx.x;

    // convert x -> fp16 (grid-stride) + zero dummy rows
    {
        int M4 = N * CH / 4;
        for (int idx = b * 256 + t; idx < M4; idx += NBLK * 256) {
            float4 v = *(const float4*)(x + (size_t)idx * 4);
            union { __half2 hh[2]; float2 f; } u;
            u.hh[0] = __floats2half2_rn(v.x, v.y);
            u.hh[1] = __floats2half2_rn(v.z, v.w);
            *(float2*)(xh + (size_t)idx * 4) = u.f;
        }
        if (b == 0 && t < 16) {
            float4 z = {0.f, 0.f, 0.f, 0.f};
            if (t < 8) ((float4*)(xh + (size_t)N * CH))[t] = z;
            else       ((float4*)(h1 + (size_t)N * CH))[t - 8] = z;
        }
    }
    // per-block bucket histogram
    h[t] = 0;
    __syncthreads();
    int s = b * per_blk;
    int e = min(s + per_blk, E);
    for (int i = s + t; i < e; i += 256)
        atomicAdd(&h[row[i] >> BKT_SHIFT], 1);
    __syncthreads();
    if (t < nbk) hoff[t * NBLK + b] = atomicAdd(&btotal[t], h[t]);
    // last-arriving block computes bucket bases
    __threadfence();
    __syncthreads();
    if (t == 0) lastflag = (atomicAdd(done, 1) == NBLK - 1);
    __syncthreads();
    if (lastflag) {
        int v = (t < nbk) ? atomicAdd(&btotal[t], 0) : 0;  // coherent read
        h[t] = v;
        __syncthreads();
        for (int off = 1; off < 256; off <<= 1) {
            int u = (t >= off) ? h[t - off] : 0;
            __syncthreads();
            h[t] += u;
            __syncthreads();
        }
        if (t < nbk) bstart[t] = h[t] - v;  // exclusive
        if (t == nbk - 1) bstart[nbk] = h[t];
    }
}

// ---- binscatter: packed (rowlocal<<17 | col) into bucket-ordered ebuf ----
__global__ __launch_bounds__(256) void k_binscatter(
    const int* __restrict__ row, const int* __restrict__ col,
    const int* __restrict__ bstart, const int* __restrict__ hoff,
    int* __restrict__ ebuf, int E, int nbk, int per_blk)
{
    __shared__ int cur[256];
    int t = threadIdx.x;
    int b = blockIdx.x;
    cur[t] = (t < nbk) ? (bstart[t] + hoff[t * NBLK + b]) : 0;
    __syncthreads();
    int s = b * per_blk;
    int e = min(s + per_blk, E);
    for (int i = s + t; i < e; i += 256) {
        int r = row[i];
        int bk = r >> BKT_SHIFT;
        int p = atomicAdd(&cur[bk], 1);
        ebuf[p] = ((r & (BKT_ROWS - 1)) << 17) | col[i];
    }
}

// ---- build: per-bucket CSR; scol staged in LDS, coalesced out ----
__global__ __launch_bounds__(256) void k_build(const int* __restrict__ bstart,
                                               const int* __restrict__ ebuf,
                                               int* __restrict__ offs,
                                               int* __restrict__ scol,
                                               int N, int E, int nbk) {
    __shared__ int cnt[BKT_ROWS];
    __shared__ int loff[BKT_ROWS];
    __shared__ int ts[256];
    __shared__ int sbuf[SCAP];
    int b = blockIdx.x, t = threadIdx.x;
    int g0 = bstart[b];
    int g1 = (b + 1 < nbk) ? bstart[b + 1] : E;
    cnt[t] = 0;
    cnt[t + 256] = 0;
    __syncthreads();
    for (int i = g0 + t; i < g1; i += 256)
        atomicAdd(&cnt[((unsigned)ebuf[i]) >> 17], 1);
    __syncthreads();
    int c0 = cnt[2 * t], c1 = cnt[2 * t + 1];
    ts[t] = c0 + c1;
    __syncthreads();
    for (int off = 1; off < 256; off <<= 1) {
        int v = (t >= off) ? ts[t - off] : 0;
        __syncthreads();
        ts[t] += v;
        __syncthreads();
    }
    int ex = ts[t] - (c0 + c1);
    loff[2 * t] = ex;
    loff[2 * t + 1] = ex + c0;
    __syncthreads();
    int r0 = b << BKT_SHIFT;
    for (int r = t; r < BKT_ROWS; r += 256)
        if (r0 + r < N) offs[r0 + r] = g0 + loff[r];
    if (b == nbk - 1 && t == 0) offs[N] = E;
    cnt[t] = 0;
    cnt[t + 256] = 0;
    __syncthreads();
    int sz = g1 - g0;
    if (sz <= SCAP) {
        for (int i = g0 + t; i < g1; i += 256) {
            unsigned v = (unsigned)ebuf[i];
            int rl = v >> 17;
            int p = atomicAdd(&cnt[rl], 1);
            sbuf[loff[rl] + p] = (int)(v & 0x1FFFFu);
        }
        __syncthreads();
        for (int i = t; i < sz; i += 256) scol[g0 + i] = sbuf[i];
    } else {
        for (int i = g0 + t; i < g1; i += 256) {
            unsigned v = (unsigned)ebuf[i];
            int rl = v >> 17;
            int p = atomicAdd(&cnt[rl], 1);
            scol[g0 + loff[rl] + p] = (int)(v & 0x1FFFFu);
        }
    }
}

// ---- mean-aggregate: one wave/node, 8 lanes/edge, 4 loads in flight ----
__global__ __launch_bounds__(256) void k_agg(const float4* __restrict__ X4,
                                             const int* __restrict__ offs,
                                             const int* __restrict__ scol,
                                             __half* __restrict__ AGGH, int N, int Em1) {
    int node = blockIdx.x * 4 + (threadIdx.x >> 6);
    int lane = threadIdx.x & 63;
    if (node >= N) return;
    int s = offs[node], e = offs[node + 1];
    int sub = lane & 7;
    int grp = lane >> 3;
    int j = s + grp;
    int i0 = scol[min(j, Em1)];       i0 = (j < e)      ? i0 : N;
    int i1 = scol[min(j + 8, Em1)];   i1 = (j + 8 < e)  ? i1 : N;
    int i2 = scol[min(j + 16, Em1)];  i2 = (j + 16 < e) ? i2 : N;
    int i3 = scol[min(j + 24, Em1)];  i3 = (j + 24 < e) ? i3 : N;
    float4 r0 = X4[(size_t)i0 * 8 + sub];
    float4 r1 = X4[(size_t)i1 * 8 + sub];
    float4 r2 = X4[(size_t)i2 * 8 + sub];
    float4 r3 = X4[(size_t)i3 * 8 + sub];
    float a[8];
#pragma unroll
    for (int k = 0; k < 8; ++k) a[k] = 0.f;
    {
        const __half2* h0 = (const __half2*)&r0;
        const __half2* h1 = (const __half2*)&r1;
        const __half2* h2 = (const __half2*)&r2;
        const __half2* h3 = (const __half2*)&r3;
#pragma unroll
        for (int p = 0; p < 4; ++p) {
            float2 f0 = __half22float2(h0[p]);
            float2 f1 = __half22float2(h1[p]);
            float2 f2 = __half22float2(h2[p]);
            float2 f3 = __half22float2(h3[p]);
            a[2 * p]     += (f0.x + f1.x) + (f2.x + f3.x);
            a[2 * p + 1] += (f0.y + f1.y) + (f2.y + f3.y);
        }
    }
    for (j += 32; j < e; j += 8) {  // rare tail: deg > 32
        float4 r = X4[(size_t)scol[j] * 8 + sub];
        const __half2* h = (const __half2*)&r;
#pragma unroll
        for (int p = 0; p < 4; ++p) {
            float2 f = __half22float2(h[p]);
            a[2 * p]     += f.x;
            a[2 * p + 1] += f.y;
        }
    }
#pragma unroll
    for (int off = 32; off >= 8; off >>= 1)
#pragma unroll
        for (int k = 0; k < 8; ++k)
            a[k] += __shfl_down(a[k], off, 64);
    if (lane < 8) {
        float inv = (e > s) ? 1.0f / (float)(e - s) : 1.0f;
        union { __half2 h[4]; float4 f; } u;
        u.h[0] = __floats2half2_rn(a[0] * inv, a[1] * inv);
        u.h[1] = __floats2half2_rn(a[2] * inv, a[3] * inv);
        u.h[2] = __floats2half2_rn(a[4] * inv, a[5] * inv);
        u.h[3] = __floats2half2_rn(a[6] * inv, a[7] * inv);
        *(float4*)(AGGH + (size_t)node * CH + sub * 8) = u.f;
    }
}

// ---- GEMM staging helpers ----
__device__ __forceinline__ void stage_a(const __half* __restrict__ A,
                                        const __half* __restrict__ AGGH,
                                        float (*As)[68], int t, int base, int N) {
    int n = t >> 2;
    int c0 = (t & 3) * 16;
    int gn = base + n;
    if (gn < N) {
        const float4* xr = (const float4*)(A + (size_t)gn * CH + c0);
        const float4* gr = (const float4*)(AGGH + (size_t)gn * CH + c0);
#pragma unroll
        for (int q = 0; q < 2; ++q) {
            union { float4 f; __half2 h[4]; } u;
            u.f = xr[q];
#pragma unroll
            for (int p = 0; p < 4; ++p) {
                As[c0 + q * 8 + 2 * p + 0][n] = __low2float(u.h[p]);
                As[c0 + q * 8 + 2 * p + 1][n] = __high2float(u.h[p]);
            }
            union { float4 f; __half2 h[4]; } g;
            g.f = gr[q];
#pragma unroll
            for (int p = 0; p < 4; ++p) {
                As[64 + c0 + q * 8 + 2 * p + 0][n] = __low2float(g.h[p]);
                As[64 + c0 + q * 8 + 2 * p + 1][n] = __high2float(g.h[p]);
            }
        }
    } else {
#pragma unroll
        for (int i = 0; i < 16; ++i) {
            As[c0 + i][n] = 0.f;
            As[64 + c0 + i][n] = 0.f;
        }
    }
}

__device__ __forceinline__ void stage_w(const float* __restrict__ W,
                                        float (*Ws)[68], int t) {
    int o = t >> 2;
    int k0 = (t & 3) * 32;
    const float4* wr = (const float4*)(W + o * 128 + k0);
#pragma unroll
    for (int q = 0; q < 8; ++q) {
        float4 v = wr[q];
        Ws[k0 + q * 4 + 0][o] = v.x;
        Ws[k0 + q * 4 + 1][o] = v.y;
        Ws[k0 + q * 4 + 2][o] = v.z;
        Ws[k0 + q * 4 + 3][o] = v.w;
    }
}

#define GEMM_CORE(As, Ws, acc, n0, o0)                                          \
    _Pragma("unroll 4")                                                          \
    for (int k = 0; k < 128; ++k) {                                              \
        float4 a = *(const float4*)&As[k][n0];                                   \
        float4 w = *(const float4*)&Ws[k][o0];                                   \
        acc[0][0] += a.x * w.x; acc[0][1] += a.x * w.y; acc[0][2] += a.x * w.z; acc[0][3] += a.x * w.w; \
        acc[1][0] += a.y * w.x; acc[1][1] += a.y * w.y; acc[1][2] += a.y * w.z; acc[1][3] += a.y * w.w; \
        acc[2][0] += a.z * w.x; acc[2][1] += a.z * w.y; acc[2][2] += a.z * w.z; acc[2][3] += a.z * w.w; \
        acc[3][0] += a.w * w.x; acc[3][1] += a.w * w.y; acc[3][2] += a.w * w.z; acc[3][3] += a.w * w.w; \
    }

// ---- layer-1: h1 = relu(cat(xh,agg).W1^T + b1), fp16 out ----
__global__ __launch_bounds__(256) void k_gemm(const __half* __restrict__ A,
                                              const __half* __restrict__ AGGH,
                                              const float* __restrict__ W,
                                              const float* __restrict__ bias,
                                              __half* __restrict__ OUT, int N) {
    __shared__ float As[128][68];
    __shared__ float Ws[128][68];
    int t = threadIdx.x;
    int base = blockIdx.x * 64;
    stage_w(W, Ws, t);
    stage_a(A, AGGH, As, t, base, N);
    __syncthreads();
    int o0 = (t & 15) * 4;
    int n0 = (t >> 4) * 4;
    float acc[4][4];
#pragma unroll
    for (int i = 0; i < 4; ++i)
#pragma unroll
        for (int jj = 0; jj < 4; ++jj) acc[i][jj] = 0.f;
    GEMM_CORE(As, Ws, acc, n0, o0);
    float4 bv = *(const float4*)&bias[o0];
#pragma unroll
    for (int i = 0; i < 4; ++i) {
        int gn = base + n0 + i;
        if (gn < N) {
            float rx = fmaxf(acc[i][0] + bv.x, 0.f);
            float ry = fmaxf(acc[i][1] + bv.y, 0.f);
            float rz = fmaxf(acc[i][2] + bv.z, 0.f);
            float rw = fmaxf(acc[i][3] + bv.w, 0.f);
            union { __half2 h[2]; float2 f; } u;
            u.h[0] = __floats2half2_rn(rx, ry);
            u.h[1] = __floats2half2_rn(rz, rw);
            *(float2*)(OUT + (size_t)gn * CH + o0) = u.f;
        }
    }
}

// ---- layer-2 + layer-3 dots ----
__global__ __launch_bounds__(256) void k_gemm2(const __half* __restrict__ A,
                                               const __half* __restrict__ AGGH,
                                               const float* __restrict__ W,
                                               const float* __restrict__ bias,
                                               const float* __restrict__ W3,
                                               float* __restrict__ tarr,
                                               float* __restrict__ sarr, int N) {
    __shared__ float As[128][68];
    __shared__ float Ws[128][68];
    int t = threadIdx.x;
    int base = blockIdx.x * 64;
    stage_w(W, Ws, t);
    stage_a(A, AGGH, As, t, base, N);
    __syncthreads();
    int o0 = (t & 15) * 4;
    int n0 = (t >> 4) * 4;
    float acc[4][4];
#pragma unroll
    for (int i = 0; i < 4; ++i)
#pragma unroll
        for (int jj = 0; jj < 4; ++jj) acc[i][jj] = 0.f;
    GEMM_CORE(As, Ws, acc, n0, o0);
    float4 bv  = *(const float4*)&bias[o0];
    float4 w3s = *(const float4*)&W3[o0];
    float4 w3a = *(const float4*)&W3[64 + o0];
#pragma unroll
    for (int i = 0; i < 4; ++i) {
        float rx = fmaxf(acc[i][0] + bv.x, 0.f);
        float ry = fmaxf(acc[i][1] + bv.y, 0.f);
        float rz = fmaxf(acc[i][2] + bv.z, 0.f);
        float rw = fmaxf(acc[i][3] + bv.w, 0.f);
        float tp = rx * w3s.x + ry * w3s.y + rz * w3s.z + rw * w3s.w;
        float sp = rx * w3a.x + ry * w3a.y + rz * w3a.z + rw * w3a.w;
#pragma unroll
        for (int off = 8; off >= 1; off >>= 1) {
            tp += __shfl_down(tp, off, 16);
            sp += __shfl_down(sp, off, 16);
        }
        int gn = base + n0 + i;
        if ((t & 15) == 0 && gn < N) {
            tarr[gn] = tp;
            sarr[gn] = sp;
        }
    }
}

// ---- final: out[n] = t[n] + mean_j s[col_j] + b3 ----
__global__ __launch_bounds__(256) void k_fin(const float* __restrict__ tarr,
                                             const float* __restrict__ sarr,
                                             const int* __restrict__ offs,
                                             const int* __restrict__ scol,
                                             const float* __restrict__ b3,
                                             float* __restrict__ out, int N) {
    int n = blockIdx.x * 256 + threadIdx.x;
    if (n >= N) return;
    int s = offs[n], e = offs[n + 1];
    float s0 = 0.f, s1 = 0.f, s2 = 0.f, s3 = 0.f;
    int j = s;
    for (; j + 4 <= e; j += 4) {
        s0 += sarr[scol[j]];
        s1 += sarr[scol[j + 1]];
        s2 += sarr[scol[j + 2]];
        s3 += sarr[scol[j + 3]];
    }
    for (; j < e; ++j) s0 += sarr[scol[j]];
    float inv = (e > s) ? 1.0f / (float)(e - s) : 1.0f;
    out[n] = tarr[n] + ((s0 + s1) + (s2 + s3)) * inv + b3[0];
}

extern "C" void kernel_launch(void* const* d_in, const int* in_sizes, int n_in,
                              void* d_out, int out_size, void* d_ws, size_t ws_size,
                              hipStream_t stream) {
    const float* x   = (const float*)d_in[0];
    const int* eidx  = (const int*)d_in[1];
    const float* W1  = (const float*)d_in[2];
    const float* b1  = (const float*)d_in[3];
    const float* W2  = (const float*)d_in[4];
    const float* b2  = (const float*)d_in[5];
    const float* W3  = (const float*)d_in[6];
    const float* b3  = (const float*)d_in[7];
    float* out = (float*)d_out;

    int N = in_sizes[0] / CH;
    int E = in_sizes[1] / 2;
    const int* row = eidx;
    const int* col = eidx + E;

    int offs_sz = ((N + 1 + 3) / 4) * 4;
    int e_sz    = ((E + 3) / 4) * 4;
    size_t tbl  = (size_t)(N + 1) * CH;

    int* offs    = (int*)d_ws;
    int* scol    = offs + offs_sz;
    __half* xh   = (__half*)(scol + e_sz);
    __half* h1   = xh + tbl;
    __half* aggh = h1 + tbl;
    float* tarr  = (float*)(aggh + (size_t)N * CH);
    float* sarr  = tarr + N;
    // sort scratch aliases aggh region (dead before aggh's first write)
    int* ebuf   = (int*)aggh;                 // E
    int nbk     = (N + BKT_ROWS - 1) >> BKT_SHIFT;
    int* hoff   = ebuf + e_sz;                // nbk*NBLK
    int* btotal = hoff + (size_t)nbk * NBLK;  // nbk
    int* done   = btotal + nbk;               // 1
    int* bstart = done + 1;                   // nbk+1

    int per_blk = (E + NBLK - 1) / NBLK;
    int abl = (N + 3) / 4;
    int gbl = (N + 63) / 64;
    int Em1 = E - 1;

    // zero btotal + done (contiguous)
    hipMemsetAsync(btotal, 0, (size_t)(nbk + 1) * sizeof(int), stream);

    // CSR build (3 dispatches)
    k_hist<<<NBLK, 256, 0, stream>>>(x, xh, h1, row, hoff, btotal, done, bstart,
                                     N, E, nbk, per_blk);
    k_binscatter<<<NBLK, 256, 0, stream>>>(row, col, bstart, hoff, ebuf, E, nbk, per_blk);
    k_build<<<nbk, 256, 0, stream>>>(bstart, ebuf, offs, scol, N, E, nbk);

    // layer 1
    k_agg<<<abl, 256, 0, stream>>>((const float4*)xh, offs, scol, aggh, N, Em1);
    k_gemm<<<gbl, 256, 0, stream>>>(xh, aggh, W1, b1, h1, N);
    // layer 2 (+ fused layer-3 dots)
    k_agg<<<abl, 256, 0, stream>>>((const float4*)h1, offs, scol, aggh, N, Em1);
    k_gemm2<<<gbl, 256, 0, stream>>>(h1, aggh, W2, b2, W3, tarr, sarr, N);
    // layer 3 finish
    k_fin<<<(N + 255) / 256, 256, 0, stream>>>(tarr, sarr, offs, scol, b3, out, N);
}

// Round 10
// 329.486 us; speedup vs baseline: 1.9801x; 1.0235x over previous
//
#include <hip/hip_runtime.h>
#include <hip/hip_fp16.h>

// GraphSAGE 3-layer. CSR via two-level counting sort with atomic bucket
// offsets (scan-free; bucket-base scan by last-arriving hist block).
// k_hist has heterogeneous block roles: blocks [0,NBLK) histogram,
// blocks [NBLK, NBLK+CBLK) fp16-convert  (R9's merged 256-block version
// was latency-bound at 4 waves/CU — fixed by giving convert 1088 blocks).
// fp16 feature tables (N+1 rows, row N zeroed). agg fp16. Layer-2 GEMM
// fuses layer-3 dots; h2 never materialized. 8 dispatches + 1 tiny memset.
//
// ws: offs | scol | xh | h1 | aggh | tarr | sarr
//     aggh region aliases: ebuf[E] | hoff[nbk*NBLK] | btotal[nbk] | done[1] | bstart[nbk+1]

#define CH 64
#define BKT_SHIFT 9
#define BKT_ROWS 512
#define NBLK 256   // hist/binscatter blocks; requires nbk <= 256
#define CBLK 1088  // convert blocks inside k_hist
#define SCAP 12288 // LDS staging capacity in k_build

// ---- hist+convert: blocks [0,NBLK) histogram + atomic offsets (+ last
//      block scans bucket bases); blocks [NBLK,NBLK+CBLK) convert x->fp16 ----
__global__ __launch_bounds__(256) void k_hist(
    const float* __restrict__ x, __half* __restrict__ xh, __half* __restrict__ h1,
    const int* __restrict__ row,
    int* __restrict__ hoff, int* __restrict__ btotal, int* __restrict__ done,
    int* __restrict__ bstart,
    int N, int E, int nbk, int per_blk)
{
    __shared__ int h[256];
    __shared__ int lastflag;
    int t = threadIdx.x;
    int b = blockIdx.x;

    if (b >= NBLK) {
        // ---- convert role: x -> fp16 (grid-stride over CBLK blocks) ----
        int cb = b - NBLK;
        int M4 = N * CH / 4;
        for (int idx = cb * 256 + t; idx < M4; idx += CBLK * 256) {
            float4 v = *(const float4*)(x + (size_t)idx * 4);
            union { __half2 hh[2]; float2 f; } u;
            u.hh[0] = __floats2half2_rn(v.x, v.y);
            u.hh[1] = __floats2half2_rn(v.z, v.w);
            *(float2*)(xh + (size_t)idx * 4) = u.f;
        }
        if (cb == 0 && t < 16) {
            float4 z = {0.f, 0.f, 0.f, 0.f};
            if (t < 8) ((float4*)(xh + (size_t)N * CH))[t] = z;
            else       ((float4*)(h1 + (size_t)N * CH))[t - 8] = z;
        }
        return;
    }
    // ---- histogram role ----
    h[t] = 0;
    __syncthreads();
    int s = b * per_blk;
    int e = min(s + per_blk, E);
    int i = s + t;
    for (; i + 768 < e; i += 1024) {  // 4 independent loads in flight
        int r0 = row[i], r1 = row[i + 256], r2 = row[i + 512], r3 = row[i + 768];
        atomicAdd(&h[r0 >> BKT_SHIFT], 1);
        atomicAdd(&h[r1 >> BKT_SHIFT], 1);
        atomicAdd(&h[r2 >> BKT_SHIFT], 1);
        atomicAdd(&h[r3 >> BKT_SHIFT], 1);
    }
    for (; i < e; i += 256)
        atomicAdd(&h[row[i] >> BKT_SHIFT], 1);
    __syncthreads();
    if (t < nbk) hoff[t * NBLK + b] = atomicAdd(&btotal[t], h[t]);
    // last-arriving hist block computes bucket bases
    __threadfence();
    __syncthreads();
    if (t == 0) lastflag = (atomicAdd(done, 1) == NBLK - 1);
    __syncthreads();
    if (lastflag) {
        int v = (t < nbk) ? atomicAdd(&btotal[t], 0) : 0;  // coherent read
        h[t] = v;
        __syncthreads();
        for (int off = 1; off < 256; off <<= 1) {
            int u = (t >= off) ? h[t - off] : 0;
            __syncthreads();
            h[t] += u;
            __syncthreads();
        }
        if (t < nbk) bstart[t] = h[t] - v;  // exclusive
        if (t == nbk - 1) bstart[nbk] = h[t];
    }
}

// ---- binscatter: packed (rowlocal<<17 | col) into bucket-ordered ebuf ----
__global__ __launch_bounds__(256) void k_binscatter(
    const int* __restrict__ row, const int* __restrict__ col,
    const int* __restrict__ bstart, const int* __restrict__ hoff,
    int* __restrict__ ebuf, int E, int nbk, int per_blk)
{
    __shared__ int cur[256];
    int t = threadIdx.x;
    int b = blockIdx.x;
    cur[t] = (t < nbk) ? (bstart[t] + hoff[t * NBLK + b]) : 0;
    __syncthreads();
    int s = b * per_blk;
    int e = min(s + per_blk, E);
    for (int i = s + t; i < e; i += 256) {
        int r = row[i];
        int bk = r >> BKT_SHIFT;
        int p = atomicAdd(&cur[bk], 1);
        ebuf[p] = ((r & (BKT_ROWS - 1)) << 17) | col[i];
    }
}

// ---- build: per-bucket CSR; scol staged in LDS, coalesced out ----
__global__ __launch_bounds__(256) void k_build(const int* __restrict__ bstart,
                                               const int* __restrict__ ebuf,
                                               int* __restrict__ offs,
                                               int* __restrict__ scol,
                                               int N, int E, int nbk) {
    __shared__ int cnt[BKT_ROWS];
    __shared__ int loff[BKT_ROWS];
    __shared__ int ts[256];
    __shared__ int sbuf[SCAP];
    int b = blockIdx.x, t = threadIdx.x;
    int g0 = bstart[b];
    int g1 = (b + 1 < nbk) ? bstart[b + 1] : E;
    cnt[t] = 0;
    cnt[t + 256] = 0;
    __syncthreads();
    for (int i = g0 + t; i < g1; i += 256)
        atomicAdd(&cnt[((unsigned)ebuf[i]) >> 17], 1);
    __syncthreads();
    int c0 = cnt[2 * t], c1 = cnt[2 * t + 1];
    ts[t] = c0 + c1;
    __syncthreads();
    for (int off = 1; off < 256; off <<= 1) {
        int v = (t >= off) ? ts[t - off] : 0;
        __syncthreads();
        ts[t] += v;
        __syncthreads();
    }
    int ex = ts[t] - (c0 + c1);
    loff[2 * t] = ex;
    loff[2 * t + 1] = ex + c0;
    __syncthreads();
    int r0 = b << BKT_SHIFT;
    for (int r = t; r < BKT_ROWS; r += 256)
        if (r0 + r < N) offs[r0 + r] = g0 + loff[r];
    if (b == nbk - 1 && t == 0) offs[N] = E;
    cnt[t] = 0;
    cnt[t + 256] = 0;
    __syncthreads();
    int sz = g1 - g0;
    if (sz <= SCAP) {
        for (int i = g0 + t; i < g1; i += 256) {
            unsigned v = (unsigned)ebuf[i];
            int rl = v >> 17;
            int p = atomicAdd(&cnt[rl], 1);
            sbuf[loff[rl] + p] = (int)(v & 0x1FFFFu);
        }
        __syncthreads();
        for (int i = t; i < sz; i += 256) scol[g0 + i] = sbuf[i];
    } else {
        for (int i = g0 + t; i < g1; i += 256) {
            unsigned v = (unsigned)ebuf[i];
            int rl = v >> 17;
            int p = atomicAdd(&cnt[rl], 1);
            scol[g0 + loff[rl] + p] = (int)(v & 0x1FFFFu);
        }
    }
}

// ---- mean-aggregate: one wave/node, 8 lanes/edge, 4 loads in flight ----
__global__ __launch_bounds__(256) void k_agg(const float4* __restrict__ X4,
                                             const int* __restrict__ offs,
                                             const int* __restrict__ scol,
                                             __half* __restrict__ AGGH, int N, int Em1) {
    int node = blockIdx.x * 4 + (threadIdx.x >> 6);
    int lane = threadIdx.x & 63;
    if (node >= N) return;
    int s = offs[node], e = offs[node + 1];
    int sub = lane & 7;
    int grp = lane >> 3;
    int j = s + grp;
    int i0 = scol[min(j, Em1)];       i0 = (j < e)      ? i0 : N;
    int i1 = scol[min(j + 8, Em1)];   i1 = (j + 8 < e)  ? i1 : N;
    int i2 = scol[min(j + 16, Em1)];  i2 = (j + 16 < e) ? i2 : N;
    int i3 = scol[min(j + 24, Em1)];  i3 = (j + 24 < e) ? i3 : N;
    float4 r0 = X4[(size_t)i0 * 8 + sub];
    float4 r1 = X4[(size_t)i1 * 8 + sub];
    float4 r2 = X4[(size_t)i2 * 8 + sub];
    float4 r3 = X4[(size_t)i3 * 8 + sub];
    float a[8];
#pragma unroll
    for (int k = 0; k < 8; ++k) a[k] = 0.f;
    {
        const __half2* h0 = (const __half2*)&r0;
        const __half2* h1 = (const __half2*)&r1;
        const __half2* h2 = (const __half2*)&r2;
        const __half2* h3 = (const __half2*)&r3;
#pragma unroll
        for (int p = 0; p < 4; ++p) {
            float2 f0 = __half22float2(h0[p]);
            float2 f1 = __half22float2(h1[p]);
            float2 f2 = __half22float2(h2[p]);
            float2 f3 = __half22float2(h3[p]);
            a[2 * p]     += (f0.x + f1.x) + (f2.x + f3.x);
            a[2 * p + 1] += (f0.y + f1.y) + (f2.y + f3.y);
        }
    }
    for (j += 32; j < e; j += 8) {  // rare tail: deg > 32
        float4 r = X4[(size_t)scol[j] * 8 + sub];
        const __half2* h = (const __half2*)&r;
#pragma unroll
        for (int p = 0; p < 4; ++p) {
            float2 f = __half22float2(h[p]);
            a[2 * p]     += f.x;
            a[2 * p + 1] += f.y;
        }
    }
#pragma unroll
    for (int off = 32; off >= 8; off >>= 1)
#pragma unroll
        for (int k = 0; k < 8; ++k)
            a[k] += __shfl_down(a[k], off, 64);
    if (lane < 8) {
        float inv = (e > s) ? 1.0f / (float)(e - s) : 1.0f;
        union { __half2 h[4]; float4 f; } u;
        u.h[0] = __floats2half2_rn(a[0] * inv, a[1] * inv);
        u.h[1] = __floats2half2_rn(a[2] * inv, a[3] * inv);
        u.h[2] = __floats2half2_rn(a[4] * inv, a[5] * inv);
        u.h[3] = __floats2half2_rn(a[6] * inv, a[7] * inv);
        *(float4*)(AGGH + (size_t)node * CH + sub * 8) = u.f;
    }
}

// ---- GEMM staging helpers ----
__device__ __forceinline__ void stage_a(const __half* __restrict__ A,
                                        const __half* __restrict__ AGGH,
                                        float (*As)[68], int t, int base, int N) {
    int n = t >> 2;
    int c0 = (t & 3) * 16;
    int gn = base + n;
    if (gn < N) {
        const float4* xr = (const float4*)(A + (size_t)gn * CH + c0);
        const float4* gr = (const float4*)(AGGH + (size_t)gn * CH + c0);
#pragma unroll
        for (int q = 0; q < 2; ++q) {
            union { float4 f; __half2 h[4]; } u;
            u.f = xr[q];
#pragma unroll
            for (int p = 0; p < 4; ++p) {
                As[c0 + q * 8 + 2 * p + 0][n] = __low2float(u.h[p]);
                As[c0 + q * 8 + 2 * p + 1][n] = __high2float(u.h[p]);
            }
            union { float4 f; __half2 h[4]; } g;
            g.f = gr[q];
#pragma unroll
            for (int p = 0; p < 4; ++p) {
                As[64 + c0 + q * 8 + 2 * p + 0][n] = __low2float(g.h[p]);
                As[64 + c0 + q * 8 + 2 * p + 1][n] = __high2float(g.h[p]);
            }
        }
    } else {
#pragma unroll
        for (int i = 0; i < 16; ++i) {
            As[c0 + i][n] = 0.f;
            As[64 + c0 + i][n] = 0.f;
        }
    }
}

__device__ __forceinline__ void stage_w(const float* __restrict__ W,
                                        float (*Ws)[68], int t) {
    int o = t >> 2;
    int k0 = (t & 3) * 32;
    const float4* wr = (const float4*)(W + o * 128 + k0);
#pragma unroll
    for (int q = 0; q < 8; ++q) {
        float4 v = wr[q];
        Ws[k0 + q * 4 + 0][o] = v.x;
        Ws[k0 + q * 4 + 1][o] = v.y;
        Ws[k0 + q * 4 + 2][o] = v.z;
        Ws[k0 + q * 4 + 3][o] = v.w;
    }
}

#define GEMM_CORE(As, Ws, acc, n0, o0)                                          \
    _Pragma("unroll 4")                                                          \
    for (int k = 0; k < 128; ++k) {                                              \
        float4 a = *(const float4*)&As[k][n0];                                   \
        float4 w = *(const float4*)&Ws[k][o0];                                   \
        acc[0][0] += a.x * w.x; acc[0][1] += a.x * w.y; acc[0][2] += a.x * w.z; acc[0][3] += a.x * w.w; \
        acc[1][0] += a.y * w.x; acc[1][1] += a.y * w.y; acc[1][2] += a.y * w.z; acc[1][3] += a.y * w.w; \
        acc[2][0] += a.z * w.x; acc[2][1] += a.z * w.y; acc[2][2] += a.z * w.z; acc[2][3] += a.z * w.w; \
        acc[3][0] += a.w * w.x; acc[3][1] += a.w * w.y; acc[3][2] += a.w * w.z; acc[3][3] += a.w * w.w; \
    }

// ---- layer-1: h1 = relu(cat(xh,agg).W1^T + b1), fp16 out ----
__global__ __launch_bounds__(256) void k_gemm(const __half* __restrict__ A,
                                              const __half* __restrict__ AGGH,
                                              const float* __restrict__ W,
                                              const float* __restrict__ bias,
                                              __half* __restrict__ OUT, int N) {
    __shared__ float As[128][68];
    __shared__ float Ws[128][68];
    int t = threadIdx.x;
    int base = blockIdx.x * 64;
    stage_w(W, Ws, t);
    stage_a(A, AGGH, As, t, base, N);
    __syncthreads();
    int o0 = (t & 15) * 4;
    int n0 = (t >> 4) * 4;
    float acc[4][4];
#pragma unroll
    for (int i = 0; i < 4; ++i)
#pragma unroll
        for (int jj = 0; jj < 4; ++jj) acc[i][jj] = 0.f;
    GEMM_CORE(As, Ws, acc, n0, o0);
    float4 bv = *(const float4*)&bias[o0];
#pragma unroll
    for (int i = 0; i < 4; ++i) {
        int gn = base + n0 + i;
        if (gn < N) {
            float rx = fmaxf(acc[i][0] + bv.x, 0.f);
            float ry = fmaxf(acc[i][1] + bv.y, 0.f);
            float rz = fmaxf(acc[i][2] + bv.z, 0.f);
            float rw = fmaxf(acc[i][3] + bv.w, 0.f);
            union { __half2 h[2]; float2 f; } u;
            u.h[0] = __floats2half2_rn(rx, ry);
            u.h[1] = __floats2half2_rn(rz, rw);
            *(float2*)(OUT + (size_t)gn * CH + o0) = u.f;
        }
    }
}

// ---- layer-2 + layer-3 dots ----
__global__ __launch_bounds__(256) void k_gemm2(const __half* __restrict__ A,
                                               const __half* __restrict__ AGGH,
                                               const float* __restrict__ W,
                                               const float* __restrict__ bias,
                                               const float* __restrict__ W3,
                                               float* __restrict__ tarr,
                                               float* __restrict__ sarr, int N) {
    __shared__ float As[128][68];
    __shared__ float Ws[128][68];
    int t = threadIdx.x;
    int base = blockIdx.x * 64;
    stage_w(W, Ws, t);
    stage_a(A, AGGH, As, t, base, N);
    __syncthreads();
    int o0 = (t & 15) * 4;
    int n0 = (t >> 4) * 4;
    float acc[4][4];
#pragma unroll
    for (int i = 0; i < 4; ++i)
#pragma unroll
        for (int jj = 0; jj < 4; ++jj) acc[i][jj] = 0.f;
    GEMM_CORE(As, Ws, acc, n0, o0);
    float4 bv  = *(const float4*)&bias[o0];
    float4 w3s = *(const float4*)&W3[o0];
    float4 w3a = *(const float4*)&W3[64 + o0];
#pragma unroll
    for (int i = 0; i < 4; ++i) {
        float rx = fmaxf(acc[i][0] + bv.x, 0.f);
        float ry = fmaxf(acc[i][1] + bv.y, 0.f);
        float rz = fmaxf(acc[i][2] + bv.z, 0.f);
        float rw = fmaxf(acc[i][3] + bv.w, 0.f);
        float tp = rx * w3s.x + ry * w3s.y + rz * w3s.z + rw * w3s.w;
        float sp = rx * w3a.x + ry * w3a.y + rz * w3a.z + rw * w3a.w;
#pragma unroll
        for (int off = 8; off >= 1; off >>= 1) {
            tp += __shfl_down(tp, off, 16);
            sp += __shfl_down(sp, off, 16);
        }
        int gn = base + n0 + i;
        if ((t & 15) == 0 && gn < N) {
            tarr[gn] = tp;
            sarr[gn] = sp;
        }
    }
}

// ---- final: out[n] = t[n] + mean_j s[col_j] + b3 ----
__global__ __launch_bounds__(256) void k_fin(const float* __restrict__ tarr,
                                             const float* __restrict__ sarr,
                                             const int* __restrict__ offs,
                                             const int* __restrict__ scol,
                                             const float* __restrict__ b3,
                                             float* __restrict__ out, int N) {
    int n = blockIdx.x * 256 + threadIdx.x;
    if (n >= N) return;
    int s = offs[n], e = offs[n + 1];
    float s0 = 0.f, s1 = 0.f, s2 = 0.f, s3 = 0.f;
    int j = s;
    for (; j + 4 <= e; j += 4) {
        s0 += sarr[scol[j]];
        s1 += sarr[scol[j + 1]];
        s2 += sarr[scol[j + 2]];
        s3 += sarr[scol[j + 3]];
    }
    for (; j < e; ++j) s0 += sarr[scol[j]];
    float inv = (e > s) ? 1.0f / (float)(e - s) : 1.0f;
    out[n] = tarr[n] + ((s0 + s1) + (s2 + s3)) * inv + b3[0];
}

extern "C" void kernel_launch(void* const* d_in, const int* in_sizes, int n_in,
                              void* d_out, int out_size, void* d_ws, size_t ws_size,
                              hipStream_t stream) {
    const float* x   = (const float*)d_in[0];
    const int* eidx  = (const int*)d_in[1];
    const float* W1  = (const float*)d_in[2];
    const float* b1  = (const float*)d_in[3];
    const float* W2  = (const float*)d_in[4];
    const float* b2  = (const float*)d_in[5];
    const float* W3  = (const float*)d_in[6];
    const float* b3  = (const float*)d_in[7];
    float* out = (float*)d_out;

    int N = in_sizes[0] / CH;
    int E = in_sizes[1] / 2;
    const int* row = eidx;
    const int* col = eidx + E;

    int offs_sz = ((N + 1 + 3) / 4) * 4;
    int e_sz    = ((E + 3) / 4) * 4;
    size_t tbl  = (size_t)(N + 1) * CH;

    int* offs    = (int*)d_ws;
    int* scol    = offs + offs_sz;
    __half* xh   = (__half*)(scol + e_sz);
    __half* h1   = xh + tbl;
    __half* aggh = h1 + tbl;
    float* tarr  = (float*)(aggh + (size_t)N * CH);
    float* sarr  = tarr + N;
    // sort scratch aliases aggh region (dead before aggh's first write)
    int* ebuf   = (int*)aggh;                 // E
    int nbk     = (N + BKT_ROWS - 1) >> BKT_SHIFT;
    int* hoff   = ebuf + e_sz;                // nbk*NBLK
    int* btotal = hoff + (size_t)nbk * NBLK;  // nbk
    int* done   = btotal + nbk;               // 1
    int* bstart = done + 1;                   // nbk+1

    int per_blk = (E + NBLK - 1) / NBLK;
    int abl = (N + 3) / 4;
    int gbl = (N + 63) / 64;
    int Em1 = E - 1;

    // zero btotal + done (contiguous)
    hipMemsetAsync(btotal, 0, (size_t)(nbk + 1) * sizeof(int), stream);

    // CSR build + convert (3 dispatches)
    k_hist<<<NBLK + CBLK, 256, 0, stream>>>(x, xh, h1, row, hoff, btotal, done,
                                            bstart, N, E, nbk, per_blk);
    k_binscatter<<<NBLK, 256, 0, stream>>>(row, col, bstart, hoff, ebuf, E, nbk, per_blk);
    k_build<<<nbk, 256, 0, stream>>>(bstart, ebuf, offs, scol, N, E, nbk);

    // layer 1
    k_agg<<<abl, 256, 0, stream>>>((const float4*)xh, offs, scol, aggh, N, Em1);
    k_gemm<<<gbl, 256, 0, stream>>>(xh, aggh, W1, b1, h1, N);
    // layer 2 (+ fused layer-3 dots)
    k_agg<<<abl, 256, 0, stream>>>((const float4*)h1, offs, scol, aggh, N, Em1);
    k_gemm2<<<gbl, 256, 0, stream>>>(h1, aggh, W2, b2, W3, tarr, sarr, N);
    // layer 3 finish
    k_fin<<<(N + 255) / 256, 256, 0, stream>>>(tarr, sarr, offs, scol, b3, out, N);
}